// Round 7
// baseline (228.620 us; speedup 1.0000x reference)
//
#include <hip/hip_runtime.h>

typedef __attribute__((ext_vector_type(4))) float f32x4;
typedef __attribute__((ext_vector_type(8))) short bf16x8;

#define OPLANE 2916     // 54*54
#define NN 23328        // 8*54*54
#define KDIM 1152       // 128*9
#define PLANE 3136      // 56*56
#define LDP 72          // padded LDS row (shorts): 144B stride -> 2-way max alias (free)

__device__ __forceinline__ unsigned short f2bf(float f) {
    unsigned u = __builtin_bit_cast(unsigned, f);
    u += 0x7fffu + ((u >> 16) & 1u);
    return (unsigned short)(u >> 16);
}
__device__ __forceinline__ float bf2f(unsigned short h) {
    unsigned u = ((unsigned)h) << 16;
    return __builtin_bit_cast(float, u);
}

// ---- k_prep: weights -> bf16, K permuted to k' = ij*128 + ic ----
__global__ __launch_bounds__(256) void k_prep(const float* __restrict__ w0,
                                              const float* __restrict__ lw,
                                              unsigned short* __restrict__ b1t,
                                              unsigned short* __restrict__ b2t) {
    int idx = blockIdx.x * 256 + threadIdx.x;   // 442368 = 147456 + 294912
    if (idx < 147456) {
        int r = idx / KDIM, k = idx - r * KDIM;
        int ij = k >> 7, ic = k & 127;
        b1t[idx] = f2bf(w0[r * KDIM + ic * 9 + ij]);
    } else {
        int j = idx - 147456;
        int r = j / KDIM, k = j - r * KDIM;
        int ij = k >> 7, ic = k & 127;
        b2t[j] = f2bf(lw[r * KDIM + ic * 9 + ij]);
    }
}

// ---- k_nhwc: x NCHW fp32 -> NHWC bf16 ----
__global__ __launch_bounds__(256) void k_nhwc(const float* __restrict__ x,
                                              unsigned short* __restrict__ xnh) {
    __shared__ unsigned short lds[56 * 132];
    const int y = blockIdx.x, b = blockIdx.y, tid = threadIdx.x;
    for (int i = tid; i < 7168; i += 256) {
        int ic = i / 56, xc = i - ic * 56;
        lds[xc * 132 + ic] = f2bf(x[(b * 128 + ic) * PLANE + y * 56 + xc]);
    }
    __syncthreads();
    for (int i = tid; i < 7168; i += 256) {
        int xc = i >> 7, ic = i & 127;
        xnh[(b * PLANE + y * 56 + xc) * 128 + ic] = lds[xc * 132 + ic];
    }
}

// ---- gemm1 (fused im2col): h = relu(im2col(xnh) * b1t^T + b0) ----
// tile 32m x 64n, 4 waves 2x2 (wave 16m x 32n), BK=64; grid (2, 784) = 1568 blocks.
__global__ __launch_bounds__(256) void k_gemm1(const unsigned short* __restrict__ xnh,
                                               const unsigned short* __restrict__ Bt,
                                               const float* __restrict__ bias,
                                               float* __restrict__ C) {
    __shared__ unsigned short As[32 * LDP];
    __shared__ unsigned short Bs[64 * LDP];
    const int tid = threadIdx.x;
    const int lane = tid & 63, wid = tid >> 6;
    const int wr = wid >> 1, wc = wid & 1;
    const int n0 = blockIdx.x * 64;
    const int m0 = blockIdx.y * 32;

    f32x4 acc[2];
    #pragma unroll
    for (int nt = 0; nt < 2; nt++) { acc[nt][0]=0.f; acc[nt][1]=0.f; acc[nt][2]=0.f; acc[nt][3]=0.f; }

    const int row = tid >> 3, q = tid & 7;        // A: 32 rows x 8 sixteenB-chunks
    const int p = m0 + row;
    const int b = p / PLANE; int rem = p - b * PLANE;
    const int y = rem / 56; const int xc = rem - y * 56;
    unsigned short* asw = &As[row * LDP + q * 8];
    const int brow = tid >> 2, bq = tid & 3;      // B: 64 rows x 4 chunks of 32B
    const unsigned short* bg = Bt + (n0 + brow) * KDIM + bq * 16;
    unsigned short* bsw = &Bs[brow * LDP + bq * 16];
    const int lm = lane & 15, lq = lane >> 4;

    #pragma unroll
    for (int it = 0; it < 18; it++) {
        const int ij = it >> 1;
        const int di = ij / 3, dj = ij - di * 3;
        const int icb = (it & 1) << 6;
        uint4 a0 = make_uint4(0u,0u,0u,0u);
        bool valid = (y + di >= 1) && (y + di <= 56) && (xc + dj >= 1) && (xc + dj <= 56);
        if (valid)
            a0 = *(const uint4*)(xnh + (p + (di - 1) * 56 + (dj - 1)) * 128 + icb + q * 8);
        uint4 bv0 = *(const uint4*)(bg + it * 64);
        uint4 bv1 = *(const uint4*)(bg + it * 64 + 8);
        __syncthreads();
        *(uint4*)asw = a0;
        *(uint4*)(bsw + 0) = bv0; *(uint4*)(bsw + 8) = bv1;
        __syncthreads();
        #pragma unroll
        for (int kk = 0; kk < 64; kk += 32) {
            bf16x8 af, bf[2];
            af = *(const bf16x8*)&As[(wr * 16 + lm) * LDP + kk + lq * 8];
            #pragma unroll
            for (int nt = 0; nt < 2; nt++)
                bf[nt] = *(const bf16x8*)&Bs[(wc * 32 + nt * 16 + lm) * LDP + kk + lq * 8];
            #pragma unroll
            for (int nt = 0; nt < 2; nt++)
                acc[nt] = __builtin_amdgcn_mfma_f32_16x16x32_bf16(af, bf[nt], acc[nt], 0, 0, 0);
        }
    }
    int m = m0 + wr * 16 + lq * 4;
    #pragma unroll
    for (int nt = 0; nt < 2; nt++) {
        int n = n0 + wc * 32 + nt * 16 + lm;
        float bb = bias[n];
        #pragma unroll
        for (int r = 0; r < 4; r++)
            C[(m + r) * 128 + n] = fmaxf(acc[nt][r] + bb, 0.f);
    }
}

// ---- k_conv2f: conv2 (NHWC h, LDS weights) + theta epilogue, fused ----
__global__ __launch_bounds__(256) void k_conv2f(const float* __restrict__ h,
                                                const float* __restrict__ w1,
                                                const int* __restrict__ check,
                                                float* __restrict__ o_out,
                                                float* __restrict__ o_th,
                                                float* __restrict__ o_ax,
                                                float* __restrict__ o_ay,
                                                float* __restrict__ sxy) {
    __shared__ float wlds[6912];        // [r][ij*128+ic]
    __shared__ float red[16 * 6 * 17];  // [pt][r][c] stride-17
    __shared__ float vals[96];
    const int tid = threadIdx.x;
    for (int idx = tid; idx < 6912; idx += 256) {
        int r = idx / KDIM, k = idx - r * KDIM;
        int ij = k >> 7, ic = k & 127;
        wlds[idx] = w1[r * KDIM + ic * 9 + ij];
    }
    __syncthreads();
    const int pt = tid >> 4, c = tid & 15;
    const int p = blockIdx.x * 16 + pt;
    int b = p / OPLANE; int rem = p - b * OPLANE; int oh = rem / 54; int ow = rem - oh * 54;
    const float4* h4 = (const float4*)h;
    const float4* w4 = (const float4*)wlds;
    float acc[6] = {0.f, 0.f, 0.f, 0.f, 0.f, 0.f};
    const int base_sp = b * PLANE + oh * 56 + ow;
    #pragma unroll
    for (int i = 0; i < 3; i++) {
        #pragma unroll
        for (int j = 0; j < 3; j++) {
            int sp = base_sp + i * 56 + j;
            float4 h0 = h4[sp * 32 + c * 2];
            float4 h1 = h4[sp * 32 + c * 2 + 1];
            int ij = i * 3 + j;
            #pragma unroll
            for (int r = 0; r < 6; r++) {
                float4 wa = w4[r * 288 + ij * 32 + c * 2];
                float4 wb = w4[r * 288 + ij * 32 + c * 2 + 1];
                acc[r] += h0.x * wa.x + h0.y * wa.y + h0.z * wa.z + h0.w * wa.w
                        + h1.x * wb.x + h1.y * wb.y + h1.z * wb.z + h1.w * wb.w;
            }
        }
    }
    #pragma unroll
    for (int r = 0; r < 6; r++) red[(pt * 6 + r) * 17 + c] = acc[r];
    __syncthreads();
    if (tid < 96) {
        const float* rp = &red[tid * 17];
        float s = 0.f;
        #pragma unroll
        for (int e = 0; e < 16; e++) s += rp[e];
        vals[tid] = s;
    }
    __syncthreads();
    if (tid < 16) {
        int p2 = blockIdx.x * 16 + tid;
        int b2 = p2 / OPLANE; int r2 = p2 - b2 * OPLANE; int oh2 = r2 / 54; int ow2 = r2 - oh2 * 54;
        float val[6];
        float s = 1.0f - (float)check[0];
        const float id6[6] = {1.f, 0.f, 0.f, 0.f, 1.f, 0.f};
        #pragma unroll
        for (int r = 0; r < 6; r++) val[r] = vals[tid * 6 + r] * s + id6[r];
        int n = (b2 * 54 + ow2) * 54 + oh2;
        #pragma unroll
        for (int r = 0; r < 6; r++) {
            o_out[((b2 * 6 + r) * 54 + oh2) * 54 + ow2] = val[r];
            o_th[n * 6 + r] = id6[r] - val[r];
        }
        const float bse[3] = {-2.f / 3.f, 0.f, 2.f / 3.f};
        #pragma unroll
        for (int i = 0; i < 3; i++)
            #pragma unroll
            for (int j = 0; j < 3; j++) {
                float gx = bse[j] * val[0] + bse[i] * val[1] + val[2];
                float gy = bse[j] * val[3] + bse[i] * val[4] + val[5];
                float ax = (gx + 1.f + (float)ow2) * (2.f / 55.f) - 1.f;
                float ay = (gy + 1.f + (float)oh2) * (2.f / 55.f) - 1.f;
                int ij = i * 3 + j;
                o_ax[n * 9 + ij] = ax;
                o_ay[n * 9 + ij] = ay;
                sxy[(n * 9 + ij) * 2 + 0] = (ax + 1.f) * 28.f - 0.5f;
                sxy[(n * 9 + ij) * 2 + 1] = (ay + 1.f) * 28.f - 0.5f;
            }
    }
}

// ---- k_sgemm: fused bilinear-gather + GEMM, K-split x2, atomic fp32 accumulate ----
// tile 64 samples x 128 o; grid (2 o, 365 s, 2 kb) = 1460 blocks; score pre-zeroed.
__global__ __launch_bounds__(256) void k_sgemm(const unsigned short* __restrict__ xnh,
                                               const unsigned short* __restrict__ Wt,
                                               const float* __restrict__ bias,
                                               const float* __restrict__ sxy,
                                               float* __restrict__ score) {
    __shared__ unsigned short Ss[64 * LDP];    // samples (gathered A-tile)
    __shared__ unsigned short Ws[128 * LDP];   // o-rows
    const int tid = threadIdx.x;
    const int lane = tid & 63, wid = tid >> 6;
    const int wr = wid >> 1, wc = wid & 1;
    const int o0 = blockIdx.x * 128;
    const int s0 = blockIdx.y * 64;
    const int kb = blockIdx.z;
    const int kb9 = kb * 9;

    f32x4 acc[4][2];
    #pragma unroll
    for (int mt = 0; mt < 4; mt++)
        #pragma unroll
        for (int nt = 0; nt < 2; nt++) { acc[mt][nt][0]=0.f; acc[mt][nt][1]=0.f; acc[mt][nt][2]=0.f; acc[mt][nt][3]=0.f; }

    const int row = tid >> 2, q = tid & 3;          // gather: 64 samples x 4 ic-sixteenths
    const int mp = min(s0 + row, NN - 1);
    const int b = mp / OPLANE; const int rr = mp - b * OPLANE;
    const int ho = rr / 54, wo = rr - (rr / 54) * 54;
    const int n = (b * 54 + wo) * 54 + ho;          // theta-order id (sxy index)
    const int xbase = b * PLANE;
    unsigned short* ssw = &Ss[row * LDP + q * 16];
    const int wrow = tid >> 1, wq = tid & 1;        // weights: 128 rows x 2 halves
    const unsigned short* wg = Wt + (o0 + wrow) * KDIM + wq * 32;
    unsigned short* wsw = &Ws[wrow * LDP + wq * 32];
    const int lm = lane & 15, lq = lane >> 4;

    int off0 = 0, off1 = 0, off2 = 0, off3 = 0;
    float wt0 = 0.f, wt1 = 0.f, wt2 = 0.f, wt3 = 0.f;

    #pragma unroll
    for (int it = kb9; it < kb9 + 9; it++) {
        const int icb = (it & 1) << 6;
        if (it == kb9 || (it & 1) == 0) {
            const int ij = it >> 1;
            float sx = sxy[(n * 9 + ij) * 2 + 0];
            float sy = sxy[(n * 9 + ij) * 2 + 1];
            float x0f = floorf(sx), y0f = floorf(sy);
            float wx = sx - x0f, wy = sy - y0f;
            int x0 = (int)x0f, y0 = (int)y0f;
            int x1 = x0 + 1, y1 = y0 + 1;
            float vx0 = (x0 >= 0 && x0 < 56) ? 1.f : 0.f;
            float vx1 = (x1 >= 0 && x1 < 56) ? 1.f : 0.f;
            float vy0 = (y0 >= 0 && y0 < 56) ? 1.f : 0.f;
            float vy1 = (y1 >= 0 && y1 < 56) ? 1.f : 0.f;
            int xc0 = min(max(x0, 0), 55), xc1 = min(max(x1, 0), 55);
            int yc0 = min(max(y0, 0), 55), yc1 = min(max(y1, 0), 55);
            off0 = (xbase + yc0 * 56 + xc0) << 7;
            off1 = (xbase + yc0 * 56 + xc1) << 7;
            off2 = (xbase + yc1 * 56 + xc0) << 7;
            off3 = (xbase + yc1 * 56 + xc1) << 7;
            wt0 = vy0 * vx0 * (1.f - wx) * (1.f - wy);
            wt1 = vy0 * vx1 * wx * (1.f - wy);
            wt2 = vy1 * vx0 * (1.f - wx) * wy;
            wt3 = vy1 * vx1 * wx * wy;
        }
        const int co = icb + q * 16;
        uint4 p0a = *(const uint4*)(xnh + off0 + co);
        uint4 p0b = *(const uint4*)(xnh + off0 + co + 8);
        uint4 p1a = *(const uint4*)(xnh + off1 + co);
        uint4 p1b = *(const uint4*)(xnh + off1 + co + 8);
        uint4 p2a = *(const uint4*)(xnh + off2 + co);
        uint4 p2b = *(const uint4*)(xnh + off2 + co + 8);
        uint4 p3a = *(const uint4*)(xnh + off3 + co);
        uint4 p3b = *(const uint4*)(xnh + off3 + co + 8);
        uint4 w0v = *(const uint4*)(wg + it * 64);
        uint4 w1v = *(const uint4*)(wg + it * 64 + 8);
        uint4 w2v = *(const uint4*)(wg + it * 64 + 16);
        uint4 w3v = *(const uint4*)(wg + it * 64 + 24);
        unsigned dw[8];
        const unsigned* d0 = (const unsigned*)&p0a;
        const unsigned* d1 = (const unsigned*)&p1a;
        const unsigned* d2 = (const unsigned*)&p2a;
        const unsigned* d3 = (const unsigned*)&p3a;
        const unsigned* e0 = (const unsigned*)&p0b;
        const unsigned* e1 = (const unsigned*)&p1b;
        const unsigned* e2 = (const unsigned*)&p2b;
        const unsigned* e3 = (const unsigned*)&p3b;
        #pragma unroll
        for (int d = 0; d < 8; d++) {
            unsigned u0 = (d < 4) ? d0[d] : e0[d - 4];
            unsigned u1 = (d < 4) ? d1[d] : e1[d - 4];
            unsigned u2 = (d < 4) ? d2[d] : e2[d - 4];
            unsigned u3 = (d < 4) ? d3[d] : e3[d - 4];
            float lo = wt0 * __builtin_bit_cast(float, u0 << 16)
                     + wt1 * __builtin_bit_cast(float, u1 << 16)
                     + wt2 * __builtin_bit_cast(float, u2 << 16)
                     + wt3 * __builtin_bit_cast(float, u3 << 16);
            float hi = wt0 * __builtin_bit_cast(float, u0 & 0xffff0000u)
                     + wt1 * __builtin_bit_cast(float, u1 & 0xffff0000u)
                     + wt2 * __builtin_bit_cast(float, u2 & 0xffff0000u)
                     + wt3 * __builtin_bit_cast(float, u3 & 0xffff0000u);
            dw[d] = (unsigned)f2bf(lo) | ((unsigned)f2bf(hi) << 16);
        }
        __syncthreads();
        *(uint4*)(ssw + 0) = *(uint4*)&dw[0];
        *(uint4*)(ssw + 8) = *(uint4*)&dw[4];
        *(uint4*)(wsw + 0)  = w0v;
        *(uint4*)(wsw + 8)  = w1v;
        *(uint4*)(wsw + 16) = w2v;
        *(uint4*)(wsw + 24) = w3v;
        __syncthreads();
        #pragma unroll
        for (int kk = 0; kk < 64; kk += 32) {
            bf16x8 wf[4], sf[2];
            #pragma unroll
            for (int mt = 0; mt < 4; mt++)
                wf[mt] = *(const bf16x8*)&Ws[(wr * 64 + mt * 16 + lm) * LDP + kk + lq * 8];
            #pragma unroll
            for (int nt = 0; nt < 2; nt++)
                sf[nt] = *(const bf16x8*)&Ss[(wc * 32 + nt * 16 + lm) * LDP + kk + lq * 8];
            #pragma unroll
            for (int mt = 0; mt < 4; mt++)
                #pragma unroll
                for (int nt = 0; nt < 2; nt++)
                    acc[mt][nt] = __builtin_amdgcn_mfma_f32_16x16x32_bf16(wf[mt], sf[nt], acc[mt][nt], 0, 0, 0);
        }
    }
    #pragma unroll
    for (int mt = 0; mt < 4; mt++) {
        #pragma unroll
        for (int r = 0; r < 4; r++) {
            int o = o0 + wr * 64 + mt * 16 + lq * 4 + r;
            float bb = (kb == 0) ? bias[o] : 0.f;
            #pragma unroll
            for (int nt = 0; nt < 2; nt++) {
                int s = s0 + wc * 32 + nt * 16 + lm;
                if (s < NN) {
                    int sb = s / OPLANE;
                    int soff = s - sb * OPLANE;
                    unsafeAtomicAdd(&score[(sb * 256 + o) * OPLANE + soff], acc[mt][nt][r] + bb);
                }
            }
        }
    }
}

extern "C" void kernel_launch(void* const* d_in, const int* in_sizes, int n_in,
                              void* d_out, int out_size, void* d_ws, size_t ws_size,
                              hipStream_t stream) {
    const float* x  = (const float*)d_in[0];
    const float* w0 = (const float*)d_in[1];
    const float* b0 = (const float*)d_in[2];
    const float* w1 = (const float*)d_in[3];
    const float* lw = (const float*)d_in[4];
    const float* lb = (const float*)d_in[5];
    const int* check = (const int*)d_in[6];

    float* out   = (float*)d_out;
    float* score = out;                    // 8*256*54*54 = 5,971,968
    float* o_th  = out + 5971968;          // 139,968
    float* o_out = out + 6111936;          // 139,968
    float* o_ax  = out + 6251904;          // 209,952
    float* o_ay  = out + 6461856;          // 209,952

    char* wsb = (char*)d_ws;
    float* h   = (float*)wsb;                                    //  12,845,056 B
    unsigned short* xnh = (unsigned short*)(wsb + 12845056);     //   6,422,528 B
    unsigned short* b1t = (unsigned short*)(wsb + 19267584);     //     294,912 B
    unsigned short* b2t = (unsigned short*)(wsb + 19562496);     //     589,824 B
    float* sxy = (float*)(wsb + 20152320);                       //   1,679,616 B -> 21.8 MB total

    hipMemsetAsync(score, 0, 5971968 * sizeof(float), stream);   // K-split atomics accumulate into zero
    k_prep<<<1728, 256, 0, stream>>>(w0, lw, b1t, b2t);
    k_nhwc<<<dim3(56, 8), 256, 0, stream>>>(x, xnh);
    k_gemm1<<<dim3(2, 784), 256, 0, stream>>>(xnh, b1t, b0, h);
    k_conv2f<<<1458, 256, 0, stream>>>(h, w1, check, o_out, o_th, o_ax, o_ay, sxy);
    k_sgemm<<<dim3(2, 365, 2), 256, 0, stream>>>(xnh, b2t, lb, sxy, score);
}

// Round 8
// 179.216 us; speedup vs baseline: 1.2757x; 1.2757x over previous
//
#include <hip/hip_runtime.h>

typedef __attribute__((ext_vector_type(4))) float f32x4;
typedef __attribute__((ext_vector_type(8))) short bf16x8;

#define OPLANE 2916     // 54*54
#define NN 23328        // 8*54*54
#define KDIM 1152       // 128*9
#define PLANE 3136      // 56*56
#define LDP 72          // padded LDS row (shorts): 144B stride -> 2-way max alias (free)

__device__ __forceinline__ unsigned short f2bf(float f) {
    unsigned u = __builtin_bit_cast(unsigned, f);
    u += 0x7fffu + ((u >> 16) & 1u);
    return (unsigned short)(u >> 16);
}
__device__ __forceinline__ float bf2f(unsigned short h) {
    unsigned u = ((unsigned)h) << 16;
    return __builtin_bit_cast(float, u);
}

// ---- k_prep: weights -> bf16, K permuted to k' = ij*128 + ic ----
__global__ __launch_bounds__(256) void k_prep(const float* __restrict__ w0,
                                              const float* __restrict__ lw,
                                              unsigned short* __restrict__ b1t,
                                              unsigned short* __restrict__ b2t) {
    int idx = blockIdx.x * 256 + threadIdx.x;   // 442368 = 147456 + 294912
    if (idx < 147456) {
        int r = idx / KDIM, k = idx - r * KDIM;
        int ij = k >> 7, ic = k & 127;
        b1t[idx] = f2bf(w0[r * KDIM + ic * 9 + ij]);
    } else {
        int j = idx - 147456;
        int r = j / KDIM, k = j - r * KDIM;
        int ij = k >> 7, ic = k & 127;
        b2t[j] = f2bf(lw[r * KDIM + ic * 9 + ij]);
    }
}

// ---- k_nhwc: x NCHW fp32 -> NHWC bf16 ----
__global__ __launch_bounds__(256) void k_nhwc(const float* __restrict__ x,
                                              unsigned short* __restrict__ xnh) {
    __shared__ unsigned short lds[56 * 132];
    const int y = blockIdx.x, b = blockIdx.y, tid = threadIdx.x;
    for (int i = tid; i < 7168; i += 256) {
        int ic = i / 56, xc = i - ic * 56;
        lds[xc * 132 + ic] = f2bf(x[(b * 128 + ic) * PLANE + y * 56 + xc]);
    }
    __syncthreads();
    for (int i = tid; i < 7168; i += 256) {
        int xc = i >> 7, ic = i & 127;
        xnh[(b * PLANE + y * 56 + xc) * 128 + ic] = lds[xc * 132 + ic];
    }
}

// ---- gemm1 (fused im2col): h = relu(im2col(xnh) * b1t^T + b0) ----
// tile 32m x 64n, 4 waves 2x2 (wave 16m x 32n), BK=64; grid (2, 784) = 1568 blocks.
__global__ __launch_bounds__(256) void k_gemm1(const unsigned short* __restrict__ xnh,
                                               const unsigned short* __restrict__ Bt,
                                               const float* __restrict__ bias,
                                               float* __restrict__ C) {
    __shared__ unsigned short As[32 * LDP];
    __shared__ unsigned short Bs[64 * LDP];
    const int tid = threadIdx.x;
    const int lane = tid & 63, wid = tid >> 6;
    const int wr = wid >> 1, wc = wid & 1;
    const int n0 = blockIdx.x * 64;
    const int m0 = blockIdx.y * 32;

    f32x4 acc[2];
    #pragma unroll
    for (int nt = 0; nt < 2; nt++) { acc[nt][0]=0.f; acc[nt][1]=0.f; acc[nt][2]=0.f; acc[nt][3]=0.f; }

    const int row = tid >> 3, q = tid & 7;        // A: 32 rows x 8 chunks of 8 shorts
    const int p = m0 + row;
    const int b = p / PLANE; int rem = p - b * PLANE;
    const int y = rem / 56; const int xc = rem - y * 56;
    unsigned short* asw = &As[row * LDP + q * 8];
    const int brow = tid >> 2, bq = tid & 3;      // B: 64 rows x 4 chunks of 16 shorts
    const unsigned short* bg = Bt + (n0 + brow) * KDIM + bq * 16;
    unsigned short* bsw = &Bs[brow * LDP + bq * 16];
    const int lm = lane & 15, lq = lane >> 4;

    #pragma unroll
    for (int it = 0; it < 18; it++) {
        const int ij = it >> 1;
        const int di = ij / 3, dj = ij - di * 3;
        const int icb = (it & 1) << 6;
        uint4 a0 = make_uint4(0u,0u,0u,0u);
        bool valid = (y + di >= 1) && (y + di <= 56) && (xc + dj >= 1) && (xc + dj <= 56);
        if (valid)
            a0 = *(const uint4*)(xnh + (p + (di - 1) * 56 + (dj - 1)) * 128 + icb + q * 8);
        uint4 bv0 = *(const uint4*)(bg + it * 64);
        uint4 bv1 = *(const uint4*)(bg + it * 64 + 8);
        __syncthreads();
        *(uint4*)asw = a0;
        *(uint4*)(bsw + 0) = bv0; *(uint4*)(bsw + 8) = bv1;
        __syncthreads();
        #pragma unroll
        for (int kk = 0; kk < 64; kk += 32) {
            bf16x8 af, bf[2];
            af = *(const bf16x8*)&As[(wr * 16 + lm) * LDP + kk + lq * 8];
            #pragma unroll
            for (int nt = 0; nt < 2; nt++)
                bf[nt] = *(const bf16x8*)&Bs[(wc * 32 + nt * 16 + lm) * LDP + kk + lq * 8];
            #pragma unroll
            for (int nt = 0; nt < 2; nt++)
                acc[nt] = __builtin_amdgcn_mfma_f32_16x16x32_bf16(af, bf[nt], acc[nt], 0, 0, 0);
        }
    }
    int m = m0 + wr * 16 + lq * 4;
    #pragma unroll
    for (int nt = 0; nt < 2; nt++) {
        int n = n0 + wc * 32 + nt * 16 + lm;
        float bb = bias[n];
        #pragma unroll
        for (int r = 0; r < 4; r++)
            C[(m + r) * 128 + n] = fmaxf(acc[nt][r] + bb, 0.f);
    }
}

// ---- k_conv2f: conv2 (NHWC h, LDS weights) + theta epilogue, fused ----
__global__ __launch_bounds__(256) void k_conv2f(const float* __restrict__ h,
                                                const float* __restrict__ w1,
                                                const int* __restrict__ check,
                                                float* __restrict__ o_out,
                                                float* __restrict__ o_th,
                                                float* __restrict__ o_ax,
                                                float* __restrict__ o_ay,
                                                float* __restrict__ sxy) {
    __shared__ float wlds[6912];        // [r][ij*128+ic]
    __shared__ float red[16 * 6 * 17];  // [pt][r][c] stride-17
    __shared__ float vals[96];
    const int tid = threadIdx.x;
    for (int idx = tid; idx < 6912; idx += 256) {
        int r = idx / KDIM, k = idx - r * KDIM;
        int ij = k >> 7, ic = k & 127;
        wlds[idx] = w1[r * KDIM + ic * 9 + ij];
    }
    __syncthreads();
    const int pt = tid >> 4, c = tid & 15;
    const int p = blockIdx.x * 16 + pt;
    int b = p / OPLANE; int rem = p - b * OPLANE; int oh = rem / 54; int ow = rem - oh * 54;
    const float4* h4 = (const float4*)h;
    const float4* w4 = (const float4*)wlds;
    float acc[6] = {0.f, 0.f, 0.f, 0.f, 0.f, 0.f};
    const int base_sp = b * PLANE + oh * 56 + ow;
    #pragma unroll
    for (int i = 0; i < 3; i++) {
        #pragma unroll
        for (int j = 0; j < 3; j++) {
            int sp = base_sp + i * 56 + j;
            float4 h0 = h4[sp * 32 + c * 2];
            float4 h1 = h4[sp * 32 + c * 2 + 1];
            int ij = i * 3 + j;
            #pragma unroll
            for (int r = 0; r < 6; r++) {
                float4 wa = w4[r * 288 + ij * 32 + c * 2];
                float4 wb = w4[r * 288 + ij * 32 + c * 2 + 1];
                acc[r] += h0.x * wa.x + h0.y * wa.y + h0.z * wa.z + h0.w * wa.w
                        + h1.x * wb.x + h1.y * wb.y + h1.z * wb.z + h1.w * wb.w;
            }
        }
    }
    #pragma unroll
    for (int r = 0; r < 6; r++) red[(pt * 6 + r) * 17 + c] = acc[r];
    __syncthreads();
    if (tid < 96) {
        const float* rp = &red[tid * 17];
        float s = 0.f;
        #pragma unroll
        for (int e = 0; e < 16; e++) s += rp[e];
        vals[tid] = s;
    }
    __syncthreads();
    if (tid < 16) {
        int p2 = blockIdx.x * 16 + tid;
        int b2 = p2 / OPLANE; int r2 = p2 - b2 * OPLANE; int oh2 = r2 / 54; int ow2 = r2 - oh2 * 54;
        float val[6];
        float s = 1.0f - (float)check[0];
        const float id6[6] = {1.f, 0.f, 0.f, 0.f, 1.f, 0.f};
        #pragma unroll
        for (int r = 0; r < 6; r++) val[r] = vals[tid * 6 + r] * s + id6[r];
        int n = (b2 * 54 + ow2) * 54 + oh2;
        #pragma unroll
        for (int r = 0; r < 6; r++) {
            o_out[((b2 * 6 + r) * 54 + oh2) * 54 + ow2] = val[r];
            o_th[n * 6 + r] = id6[r] - val[r];
        }
        const float bse[3] = {-2.f / 3.f, 0.f, 2.f / 3.f};
        #pragma unroll
        for (int i = 0; i < 3; i++)
            #pragma unroll
            for (int j = 0; j < 3; j++) {
                float gx = bse[j] * val[0] + bse[i] * val[1] + val[2];
                float gy = bse[j] * val[3] + bse[i] * val[4] + val[5];
                float ax = (gx + 1.f + (float)ow2) * (2.f / 55.f) - 1.f;
                float ay = (gy + 1.f + (float)oh2) * (2.f / 55.f) - 1.f;
                int ij = i * 3 + j;
                o_ax[n * 9 + ij] = ax;
                o_ay[n * 9 + ij] = ay;
                sxy[(n * 9 + ij) * 2 + 0] = (ax + 1.f) * 28.f - 0.5f;
                sxy[(n * 9 + ij) * 2 + 1] = (ay + 1.f) * 28.f - 0.5f;
            }
    }
}

// ---- k_sgemm: fused bilinear-gather + GEMM, tile 32 samples x 128 o ----
// grid (2 o-halves, 729 s-tiles) = 1458 blocks (5.7/CU); no atomics, plain stores.
__global__ __launch_bounds__(256) void k_sgemm(const unsigned short* __restrict__ xnh,
                                               const unsigned short* __restrict__ Wt,
                                               const float* __restrict__ bias,
                                               const float* __restrict__ sxy,
                                               float* __restrict__ score) {
    __shared__ unsigned short Ss[32 * LDP];    // samples (gathered A-tile)
    __shared__ unsigned short Ws[128 * LDP];   // o-rows
    const int tid = threadIdx.x;
    const int lane = tid & 63, wid = tid >> 6;
    const int wr = wid >> 1, wc = wid & 1;     // wr: o-64-half, wc: s-16-half
    const int o0 = blockIdx.x * 128;
    const int s0 = blockIdx.y * 32;            // 729 tiles, exact (23328 = 32*729)

    f32x4 acc[4];
    #pragma unroll
    for (int mt = 0; mt < 4; mt++) { acc[mt][0]=0.f; acc[mt][1]=0.f; acc[mt][2]=0.f; acc[mt][3]=0.f; }

    const int row = tid >> 3, q = tid & 7;     // gather: 32 samples x 8 ic-eighths
    const int mp = s0 + row;                   // score-linear sample id
    const int b = mp / OPLANE; const int rr = mp - b * OPLANE;
    const int ho = rr / 54, wo = rr - (rr / 54) * 54;
    const int n = (b * 54 + wo) * 54 + ho;     // theta-order id (sxy index)
    const int xbase = b * PLANE;
    unsigned short* ssw = &Ss[row * LDP + q * 8];
    const int wrow = tid >> 1, wq = tid & 1;   // weights: 128 rows x 2 halves of 32 shorts
    const unsigned short* wg = Wt + (o0 + wrow) * KDIM + wq * 32;
    unsigned short* wsw = &Ws[wrow * LDP + wq * 32];
    const int lm = lane & 15, lq = lane >> 4;

    int off0 = 0, off1 = 0, off2 = 0, off3 = 0;
    float wt0 = 0.f, wt1 = 0.f, wt2 = 0.f, wt3 = 0.f;

    #pragma unroll
    for (int it = 0; it < 18; it++) {
        const int icb = (it & 1) << 6;
        if ((it & 1) == 0) {
            const int ij = it >> 1;
            float sx = sxy[(n * 9 + ij) * 2 + 0];
            float sy = sxy[(n * 9 + ij) * 2 + 1];
            float x0f = floorf(sx), y0f = floorf(sy);
            float wx = sx - x0f, wy = sy - y0f;
            int x0 = (int)x0f, y0 = (int)y0f;
            int x1 = x0 + 1, y1 = y0 + 1;
            float vx0 = (x0 >= 0 && x0 < 56) ? 1.f : 0.f;
            float vx1 = (x1 >= 0 && x1 < 56) ? 1.f : 0.f;
            float vy0 = (y0 >= 0 && y0 < 56) ? 1.f : 0.f;
            float vy1 = (y1 >= 0 && y1 < 56) ? 1.f : 0.f;
            int xc0 = min(max(x0, 0), 55), xc1 = min(max(x1, 0), 55);
            int yc0 = min(max(y0, 0), 55), yc1 = min(max(y1, 0), 55);
            off0 = (xbase + yc0 * 56 + xc0) << 7;
            off1 = (xbase + yc0 * 56 + xc1) << 7;
            off2 = (xbase + yc1 * 56 + xc0) << 7;
            off3 = (xbase + yc1 * 56 + xc1) << 7;
            wt0 = vy0 * vx0 * (1.f - wx) * (1.f - wy);
            wt1 = vy0 * vx1 * wx * (1.f - wy);
            wt2 = vy1 * vx0 * (1.f - wx) * wy;
            wt3 = vy1 * vx1 * wx * wy;
        }
        const int co = icb + q * 8;
        uint4 p0 = *(const uint4*)(xnh + off0 + co);
        uint4 p1 = *(const uint4*)(xnh + off1 + co);
        uint4 p2 = *(const uint4*)(xnh + off2 + co);
        uint4 p3 = *(const uint4*)(xnh + off3 + co);
        uint4 w0v = *(const uint4*)(wg + it * 64);
        uint4 w1v = *(const uint4*)(wg + it * 64 + 8);
        uint4 w2v = *(const uint4*)(wg + it * 64 + 16);
        uint4 w3v = *(const uint4*)(wg + it * 64 + 24);
        unsigned dw[4];
        const unsigned* d0 = (const unsigned*)&p0;
        const unsigned* d1 = (const unsigned*)&p1;
        const unsigned* d2 = (const unsigned*)&p2;
        const unsigned* d3 = (const unsigned*)&p3;
        #pragma unroll
        for (int d = 0; d < 4; d++) {
            float lo = wt0 * __builtin_bit_cast(float, d0[d] << 16)
                     + wt1 * __builtin_bit_cast(float, d1[d] << 16)
                     + wt2 * __builtin_bit_cast(float, d2[d] << 16)
                     + wt3 * __builtin_bit_cast(float, d3[d] << 16);
            float hi = wt0 * __builtin_bit_cast(float, d0[d] & 0xffff0000u)
                     + wt1 * __builtin_bit_cast(float, d1[d] & 0xffff0000u)
                     + wt2 * __builtin_bit_cast(float, d2[d] & 0xffff0000u)
                     + wt3 * __builtin_bit_cast(float, d3[d] & 0xffff0000u);
            dw[d] = (unsigned)f2bf(lo) | ((unsigned)f2bf(hi) << 16);
        }
        __syncthreads();
        *(uint4*)ssw = *(uint4*)&dw[0];
        *(uint4*)(wsw + 0)  = w0v;
        *(uint4*)(wsw + 8)  = w1v;
        *(uint4*)(wsw + 16) = w2v;
        *(uint4*)(wsw + 24) = w3v;
        __syncthreads();
        #pragma unroll
        for (int kk = 0; kk < 64; kk += 32) {
            bf16x8 wf[4], sf;
            #pragma unroll
            for (int mt = 0; mt < 4; mt++)
                wf[mt] = *(const bf16x8*)&Ws[(wr * 64 + mt * 16 + lm) * LDP + kk + lq * 8];
            sf = *(const bf16x8*)&Ss[(wc * 16 + lm) * LDP + kk + lq * 8];
            #pragma unroll
            for (int mt = 0; mt < 4; mt++)
                acc[mt] = __builtin_amdgcn_mfma_f32_16x16x32_bf16(wf[mt], sf, acc[mt], 0, 0, 0);
        }
    }
    #pragma unroll
    for (int mt = 0; mt < 4; mt++) {
        #pragma unroll
        for (int r = 0; r < 4; r++) {
            int o = o0 + wr * 64 + mt * 16 + lq * 4 + r;
            float bb = bias[o];
            int s = s0 + wc * 16 + lm;
            int sb = s / OPLANE;
            int soff = s - sb * OPLANE;
            score[(sb * 256 + o) * OPLANE + soff] = acc[mt][r] + bb;
        }
    }
}

extern "C" void kernel_launch(void* const* d_in, const int* in_sizes, int n_in,
                              void* d_out, int out_size, void* d_ws, size_t ws_size,
                              hipStream_t stream) {
    const float* x  = (const float*)d_in[0];
    const float* w0 = (const float*)d_in[1];
    const float* b0 = (const float*)d_in[2];
    const float* w1 = (const float*)d_in[3];
    const float* lw = (const float*)d_in[4];
    const float* lb = (const float*)d_in[5];
    const int* check = (const int*)d_in[6];

    float* out   = (float*)d_out;
    float* score = out;                    // 8*256*54*54 = 5,971,968
    float* o_th  = out + 5971968;          // 139,968
    float* o_out = out + 6111936;          // 139,968
    float* o_ax  = out + 6251904;          // 209,952
    float* o_ay  = out + 6461856;          // 209,952

    char* wsb = (char*)d_ws;
    float* h   = (float*)wsb;                                    //  12,845,056 B
    unsigned short* xnh = (unsigned short*)(wsb + 12845056);     //   6,422,528 B
    unsigned short* b1t = (unsigned short*)(wsb + 19267584);     //     294,912 B
    unsigned short* b2t = (unsigned short*)(wsb + 19562496);     //     589,824 B
    float* sxy = (float*)(wsb + 20152320);                       //   1,679,616 B -> 21.8 MB total

    k_prep<<<1728, 256, 0, stream>>>(w0, lw, b1t, b2t);
    k_nhwc<<<dim3(56, 8), 256, 0, stream>>>(x, xnh);
    k_gemm1<<<dim3(2, 784), 256, 0, stream>>>(xnh, b1t, b0, h);
    k_conv2f<<<1458, 256, 0, stream>>>(h, w1, check, o_out, o_th, o_ax, o_ay, sxy);
    k_sgemm<<<dim3(2, 729), 256, 0, stream>>>(xnh, b2t, lb, sxy, score);
}